// Round 5
// baseline (143.592 us; speedup 1.0000x reference)
//
#include <hip/hip_runtime.h>
#include <math.h>

#define NH   32
#define NKVH 8
#define HD   64
#define WIN  256
#define BB   2
#define SS   2048

typedef short short8 __attribute__((ext_vector_type(8)));
typedef float f32x4  __attribute__((ext_vector_type(4)));

#define NEG_LN_1E4_32 (-0.28782313662425572f)   // -ln(10000)/32

__device__ __forceinline__ ushort f2bf(float x) {
    union { float f; unsigned u; } v; v.f = x;
    unsigned u = v.u + 0x7FFF + ((v.u >> 16) & 1);   // RNE
    return (ushort)(u >> 16);
}

// ---- pre-pass: RoPE K -> bf16 [b][kvh][s][d]; V -> bf16 transposed [b][kvh][d][s] ----
__global__ __launch_bounds__(256) void prep_kv(const float* __restrict__ K,
                                               const float* __restrict__ V,
                                               ushort* __restrict__ Kr,
                                               ushort* __restrict__ Vt) {
    __shared__ ushort tile[32][66];
    const int bidx = blockIdx.x;               // (b, kvh, stile): 2*8*64
    const int s0  = (bidx & 63) * 32;
    const int kvh = (bidx >> 6) & 7;
    const int b   = bidx >> 9;
    const int t   = threadIdx.x;

    // K: pair-based RoPE, no shuffles. thread: dim-pair d/d+32, rows r+8i
    {
        int d = t & 31, r = t >> 5;
        float inv = __expf((float)d * NEG_LN_1E4_32);
#pragma unroll
        for (int i = 0; i < 4; ++i) {
            int s = s0 + r + 8 * i;
            const float* krow = K + (size_t)(b * SS + s) * (NKVH * HD) + kvh * HD;
            float x1 = krow[d], x2 = krow[d + 32];
            float sn, cs;
            __sincosf((float)s * inv, &sn, &cs);
            ushort* kout = Kr + ((size_t)(b * NKVH + kvh) * SS + s) * HD;
            kout[d]      = f2bf(x1 * cs - x2 * sn);
            kout[d + 32] = f2bf(x2 * cs + x1 * sn);
        }
    }

    // V: load coalesced, transpose via LDS, ushort4 stores
    {
        int dv = t & 63, rv = t >> 6;
#pragma unroll
        for (int i = 0; i < 8; ++i) {
            int sl = rv + 4 * i;
            tile[sl][dv] = f2bf(V[(size_t)(b * SS + s0 + sl) * (NKVH * HD) + kvh * HD + dv]);
        }
    }
    __syncthreads();
    {
        int g = t & 7, dr0 = t >> 3;
#pragma unroll
        for (int half = 0; half < 2; ++half) {
            int dr = dr0 + 32 * half;
            ushort4 u = make_ushort4(tile[4 * g + 0][dr], tile[4 * g + 1][dr],
                                     tile[4 * g + 2][dr], tile[4 * g + 3][dr]);
            *(ushort4*)(Vt + ((size_t)(b * NKVH + kvh) * HD + dr) * SS + s0 + 4 * g) = u;
        }
    }
}

// ---- main: wave = 32 queries; block = 4 waves = 2 head-replicas x 2 k-splits ----
__global__ __launch_bounds__(256, 4) void attn_mfma(const float* __restrict__ Q,
                                                    const ushort* __restrict__ Kr,
                                                    const ushort* __restrict__ Vt,
                                                    float* __restrict__ O) {
    __shared__ ushort Pl[4][2][16][40];     // [wave][tile][query][key(32)+pad], single-buffered
    __shared__ float  Cb[2][64][36];        // [replica-pair][lane][32 acc + 2 psum + pad]

    const int wv = threadIdx.x >> 6, lane = threadIdx.x & 63;
    const int lo16 = lane & 15, quad = lane >> 4;
    const int ks   = wv & 1;                // k-split index
    const int pair = wv >> 1;               // replica within block
    const int bidx = blockIdx.x;            // (b, kvh, hpair, qblk): 2*8*2*64
    const int qblk  = bidx & 63;
    const int hpair = (bidx >> 6) & 1;
    const int kvh   = (bidx >> 7) & 7;
    const int b     = bidx >> 10;
    const int h     = kvh * 4 + hpair * 2 + pair;
    const int q0    = qblk * 32;

    // ---- Q load + RoPE + scale -> MFMA B-operand frags (dims 0-31, 32-63) ----
    short8 aq[2][2];
#pragma unroll
    for (int t = 0; t < 2; ++t) {
        int qi = q0 + t * 16 + lo16;
        const float* qrow = Q + (size_t)(b * SS + qi) * (NH * HD) + h * HD;
        float lo[8], hi[8];
        *(float4*)(lo)     = *(const float4*)(qrow + quad * 8);
        *(float4*)(lo + 4) = *(const float4*)(qrow + quad * 8 + 4);
        *(float4*)(hi)     = *(const float4*)(qrow + 32 + quad * 8);
        *(float4*)(hi + 4) = *(const float4*)(qrow + 32 + quad * 8 + 4);
#pragma unroll
        for (int j = 0; j < 8; ++j) {
            float invf = __expf((float)(quad * 8 + j) * NEG_LN_1E4_32);
            float sn, cs;
            __sincosf((float)qi * invf, &sn, &cs);
            aq[t][0][j] = (short)f2bf((lo[j] * cs - hi[j] * sn) * 0.125f);
            aq[t][1][j] = (short)f2bf((hi[j] * cs + lo[j] * sn) * 0.125f);
        }
    }

    const ushort* kbase = Kr + (size_t)(b * NKVH + kvh) * SS * HD;
    const ushort* vbase = Vt + (size_t)(b * NKVH + kvh) * HD * SS;

    f32x4 acc[2][4];
#pragma unroll
    for (int t = 0; t < 2; ++t)
#pragma unroll
        for (int i = 0; i < 4; ++i) acc[t][i] = (f32x4){0.f, 0.f, 0.f, 0.f};
    float psum[2] = {0.f, 0.f};

    int klo = q0 - WIN; if (klo < 0) klo = 0;
    const int khi = q0 + 31;
    const int kb0 = klo + 32 * ks;          // this wave's chunks: kb0, kb0+64, ...

    short8 kcur[4], knxt[4];
    {
        int key0 = kb0 + lo16, key1 = key0 + 16;
        kcur[0] = *(const short8*)(kbase + (size_t)key0 * HD + quad * 8);
        kcur[1] = *(const short8*)(kbase + (size_t)key0 * HD + 32 + quad * 8);
        kcur[2] = *(const short8*)(kbase + (size_t)key1 * HD + quad * 8);
        kcur[3] = *(const short8*)(kbase + (size_t)key1 * HD + 32 + quad * 8);
    }

    for (int kb = kb0; kb <= khi; kb += 64) {
        // ---- QK^T MFMAs (S^T: C[row=key][col=query]) ----
        const f32x4 z = {0.f, 0.f, 0.f, 0.f};
        f32x4 s00 = __builtin_amdgcn_mfma_f32_16x16x32_bf16(kcur[0], aq[0][0], z,   0, 0, 0);
        s00       = __builtin_amdgcn_mfma_f32_16x16x32_bf16(kcur[1], aq[0][1], s00, 0, 0, 0);
        f32x4 s01 = __builtin_amdgcn_mfma_f32_16x16x32_bf16(kcur[2], aq[0][0], z,   0, 0, 0);
        s01       = __builtin_amdgcn_mfma_f32_16x16x32_bf16(kcur[3], aq[0][1], s01, 0, 0, 0);
        f32x4 s10 = __builtin_amdgcn_mfma_f32_16x16x32_bf16(kcur[0], aq[1][0], z,   0, 0, 0);
        s10       = __builtin_amdgcn_mfma_f32_16x16x32_bf16(kcur[1], aq[1][1], s10, 0, 0, 0);
        f32x4 s11 = __builtin_amdgcn_mfma_f32_16x16x32_bf16(kcur[2], aq[1][0], z,   0, 0, 0);
        s11       = __builtin_amdgcn_mfma_f32_16x16x32_bf16(kcur[3], aq[1][1], s11, 0, 0, 0);

        // ---- prefetch next chunk K + this chunk V (independent of MFMA results) ----
        {
            int key0 = kb + 64 + lo16; if (key0 > SS - 1) key0 = SS - 1;
            int key1 = key0 + 16;      if (key1 > SS - 1) key1 = SS - 1;
            knxt[0] = *(const short8*)(kbase + (size_t)key0 * HD + quad * 8);
            knxt[1] = *(const short8*)(kbase + (size_t)key0 * HD + 32 + quad * 8);
            knxt[2] = *(const short8*)(kbase + (size_t)key1 * HD + quad * 8);
            knxt[3] = *(const short8*)(kbase + (size_t)key1 * HD + 32 + quad * 8);
        }
        short8 vf[4];
        {
            int sb2 = kb + quad * 8;
#pragma unroll
            for (int i = 0; i < 4; ++i)
                vf[i] = *(const short8*)(vbase + (size_t)(i * 16 + lo16) * SS + sb2);
        }

        // ---- mask + exp (no max subtraction: |s| small, fp32-safe) ----
#pragma unroll
        for (int t = 0; t < 2; ++t) {
            const f32x4 sa = t ? s10 : s00;
            const f32x4 sb = t ? s11 : s01;
            const int qtmin = q0 + t * 16;
            const int myq   = qtmin + lo16;
            float p[8];
            if ((kb + 31 > qtmin) || (kb < qtmin + 15 - WIN)) {   // boundary chunk
#pragma unroll
                for (int r = 0; r < 4; ++r) {
                    int key0 = kb + quad * 4 + r;
                    int key1 = key0 + 16;
                    p[r]     = (key0 <= myq && key0 >= myq - WIN) ? __expf(sa[r]) : 0.f;
                    p[4 + r] = (key1 <= myq && key1 >= myq - WIN) ? __expf(sb[r]) : 0.f;
                }
            } else {                                              // interior
#pragma unroll
                for (int r = 0; r < 4; ++r) { p[r] = __expf(sa[r]); p[4 + r] = __expf(sb[r]); }
            }
            psum[t] += ((p[0] + p[1]) + (p[2] + p[3])) + ((p[4] + p[5]) + (p[6] + p[7]));
            ushort4 u0 = make_ushort4(f2bf(p[0]), f2bf(p[1]), f2bf(p[2]), f2bf(p[3]));
            ushort4 u1 = make_ushort4(f2bf(p[4]), f2bf(p[5]), f2bf(p[6]), f2bf(p[7]));
            *(ushort4*)&Pl[wv][t][lo16][quad * 4]      = u0;
            *(ushort4*)&Pl[wv][t][lo16][16 + quad * 4] = u1;
        }

        // wait own LDS writes; single buffer => WAR dep keeps next-iter writes ordered
        __asm__ volatile("s_waitcnt lgkmcnt(0)" ::: "memory");
        short8 ap0 = *(const short8*)&Pl[wv][0][lo16][quad * 8];
        short8 ap1 = *(const short8*)&Pl[wv][1][lo16][quad * 8];

#pragma unroll
        for (int i = 0; i < 4; ++i)
            acc[0][i] = __builtin_amdgcn_mfma_f32_16x16x32_bf16(ap0, vf[i], acc[0][i], 0, 0, 0);
#pragma unroll
        for (int i = 0; i < 4; ++i)
            acc[1][i] = __builtin_amdgcn_mfma_f32_16x16x32_bf16(ap1, vf[i], acc[1][i], 0, 0, 0);

#pragma unroll
        for (int i = 0; i < 4; ++i) kcur[i] = knxt[i];
    }

    // ---- per-wave psum reduction (over quads) ----
    float ps[2];
#pragma unroll
    for (int t = 0; t < 2; ++t) {
        float v = psum[t];
        v += __shfl_xor(v, 16, 64);
        v += __shfl_xor(v, 32, 64);
        ps[t] = v;                           // per-lane: this wave's total for query lo16
    }

    // ---- combine the two k-split waves of this replica pair ----
    if (ks == 1) {
        float* cb = &Cb[pair][lane][0];
#pragma unroll
        for (int t = 0; t < 2; ++t)
#pragma unroll
            for (int i = 0; i < 4; ++i)
                *(f32x4*)(cb + (t * 4 + i) * 4) = acc[t][i];
        cb[32] = ps[0]; cb[33] = ps[1];
    }
    __syncthreads();
    if (ks == 0) {
        const float* cb = &Cb[pair][lane][0];
#pragma unroll
        for (int t = 0; t < 2; ++t)
#pragma unroll
            for (int i = 0; i < 4; ++i)
                acc[t][i] += *(const f32x4*)(cb + (t * 4 + i) * 4);
        ps[0] += cb[32]; ps[1] += cb[33];

#pragma unroll
        for (int t = 0; t < 2; ++t) {
#pragma unroll
            for (int r = 0; r < 4; ++r) {
                float invr = 1.f / __shfl(ps[t], quad * 4 + r, 16);
                int qr = q0 + t * 16 + quad * 4 + r;
                size_t orow = ((size_t)(b * SS + qr) * NH + h) * HD;
                O[orow + 0 * 16 + lo16] = acc[t][0][r] * invr;
                O[orow + 1 * 16 + lo16] = acc[t][1][r] * invr;
                O[orow + 2 * 16 + lo16] = acc[t][2][r] * invr;
                O[orow + 3 * 16 + lo16] = acc[t][3][r] * invr;
            }
        }
    }
}

// ---------- fallback (no workspace): scalar kernel ----------
__device__ __forceinline__ float wave_sum(float x) {
#pragma unroll
    for (int off = 32; off > 0; off >>= 1) x += __shfl_xor(x, off, 64);
    return x;
}

__global__ __launch_bounds__(256) void attn_scalar(const float* __restrict__ Q,
                                                   const float* __restrict__ K,
                                                   const float* __restrict__ V,
                                                   float* __restrict__ O) {
    int wave = blockIdx.x * 4 + (threadIdx.x >> 6);
    int lane = threadIdx.x & 63;
    int q  = wave % SS;
    int bh = wave / SS;
    int h  = bh % NH;
    int b  = bh / NH;
    int kvh = h >> 2;

    float inv = __expf((float)(lane & 31) * NEG_LN_1E4_32);
    float sn, cs;
    __sincosf((float)q * inv, &sn, &cs);

    float qv = Q[(size_t)(b * SS + q) * (NH * HD) + h * HD + lane];
    float qpart = __shfl(qv, lane ^ 32, 64);
    float qrot = (qv * cs + ((lane < 32) ? -qpart : qpart) * sn) * 0.125f;

    const float* vbase = V + (size_t)b * SS * (NKVH * HD) + kvh * HD;
    float m = -1e30f, l = 0.f, acc = 0.f;
    int k0 = q - WIN; if (k0 < 0) k0 = 0;
    for (int k = k0; k <= q; ++k) {
        float kraw = K[(size_t)(b * SS + k) * (NKVH * HD) + kvh * HD + lane];
        float kpart = __shfl(kraw, lane ^ 32, 64);
        float ksn, kcs;
        __sincosf((float)k * inv, &ksn, &kcs);
        float kv = kraw * kcs + ((lane < 32) ? -kpart : kpart) * ksn;
        float vv = vbase[(size_t)k * (NKVH * HD) + lane];
        float score = wave_sum(qrot * kv);
        float mnew  = fmaxf(m, score);
        float alpha = __expf(m - mnew);
        float p     = __expf(score - mnew);
        l   = l * alpha + p;
        acc = acc * alpha + p * vv;
        m   = mnew;
    }
    O[(((size_t)(b * SS + q) * NH) + h) * HD + lane] = acc / l;
}

extern "C" void kernel_launch(void* const* d_in, const int* in_sizes, int n_in,
                              void* d_out, int out_size, void* d_ws, size_t ws_size,
                              hipStream_t stream) {
    const float* Q = (const float*)d_in[0];
    const float* K = (const float*)d_in[1];
    const float* V = (const float*)d_in[2];
    float* O = (float*)d_out;

    size_t kv_elems = (size_t)BB * NKVH * SS * HD;   // 2M elements
    size_t need = 2 * kv_elems * sizeof(ushort);     // 8 MB

    if (ws_size >= need) {
        ushort* Kr = (ushort*)d_ws;
        ushort* Vt = Kr + kv_elems;
        prep_kv<<<BB * NKVH * (SS / 32), 256, 0, stream>>>(K, V, Kr, Vt);
        attn_mfma<<<BB * NKVH * 2 * (SS / 32), 256, 0, stream>>>(Q, Kr, Vt, O);
    } else {
        attn_scalar<<<(BB * NH * SS) / 4, 256, 0, stream>>>(Q, K, V, O);
    }
}